// Round 17
// baseline (204.950 us; speedup 1.0000x reference)
//
#include <hip/hip_runtime.h>
#include <hip/hip_bf16.h>
#include <stdint.h>

typedef __attribute__((ext_vector_type(8))) short bf16x8;
typedef __attribute__((ext_vector_type(4))) float f32x4;
typedef __attribute__((ext_vector_type(16))) float f32x16;
typedef __attribute__((ext_vector_type(8))) unsigned short ushort8;
typedef __attribute__((ext_vector_type(4))) unsigned short ushort4v;
typedef __attribute__((ext_vector_type(4))) unsigned int u32x4;
typedef __attribute__((ext_vector_type(2))) unsigned int u32x2;

#define DEVINL __device__ __forceinline__

static constexpr int BB  = 4;
static constexpr int SS  = 2048;
static constexpr int HID = 1024;
static constexpr int NH  = 16;
static constexpr int DH  = 64;

DEVINL unsigned short f2bf(float f) {
  unsigned u = __builtin_bit_cast(unsigned, f);
  u += 0x7fffu + ((u >> 16) & 1u);   // RNE
  return (unsigned short)(u >> 16);
}

DEVINL unsigned cvt_pk_bf16(float lo, float hi) {
  unsigned r;
  asm("v_cvt_pk_bf16_f32 %0, %1, %2" : "=v"(r) : "v"(lo), "v"(hi));
  return r;
}

DEVINL void gload_lds16(const void* g, void* lds) {
  __builtin_amdgcn_global_load_lds(
      (__attribute__((address_space(1))) unsigned int*)(g),
      (__attribute__((address_space(3))) unsigned int*)(lds), 16, 0, 0);
}

// all 4 weight matrices in one launch; dst = [4][1M] (Wq,Wk,Wv,Wo)
__global__ void cvt4_weights(const float* __restrict__ a,
                             const float* __restrict__ b,
                             const float* __restrict__ c,
                             const float* __restrict__ d,
                             unsigned short* __restrict__ dst) {
  int which = blockIdx.x >> 10;
  const float* src = which == 0 ? a : which == 1 ? b : which == 2 ? c : d;
  int i = ((blockIdx.x & 1023) * 256 + threadIdx.x) * 4;
  float4 v = *(const float4*)(src + i);
  ushort4v h;
  h.x = f2bf(v.x); h.y = f2bf(v.y); h.z = f2bf(v.z); h.w = f2bf(v.w);
  *(ushort4v*)(dst + which * 1048576 + i) = h;
}

// ---------------- grouped QKV GEMM, T4 counted-vmcnt (R15 GREEN) -----------
__launch_bounds__(256)
__global__ void gemm_qkv(const float* __restrict__ qp,
                         const float* __restrict__ kp,
                         const float* __restrict__ vp,
                         const unsigned short* __restrict__ W,
                         const float* __restrict__ bq,
                         const float* __restrict__ bk,
                         const float* __restrict__ bv,
                         unsigned short* __restrict__ dstQK,
                         unsigned short* __restrict__ Vt, float sclq) {
  __shared__ __align__(16) unsigned char As[16384];
  __shared__ __align__(16) unsigned char Bs[2][16384];
  const int cpx = gridDim.x >> 3;
  const int bid = (blockIdx.x & 7) * cpx + (blockIdx.x >> 3);
  const int which = bid / 512;
  const int tile = bid - which * 512;
  const int bm = tile >> 3, bn = tile & 7;
  const int m0 = bm << 7, n0 = bn << 7;
  const int K = 1024, N = 1024;
  const float* Af = which == 0 ? qp : which == 1 ? kp : vp;
  const unsigned short* Bw = W + which * 1048576;
  const float* bias = which == 0 ? bq : which == 1 ? bk : bv;
  const float osc = which == 0 ? sclq : 1.0f;

  const int t = threadIdx.x, lane = t & 63, wv = t >> 6;
  const int wr = wv >> 1, wc = wv & 1;
  const int l15 = lane & 15, l4 = lane >> 4;

  f32x4 acc[4][4] = {};
  float4 ar[8];  // A fp32 prefetch (one K-step ahead)

  auto LOAD_A = [&](int k0) {
#pragma unroll
    for (int j = 0; j < 8; ++j) {
      int qid = t + j * 256;
      int row = qid >> 4;
      int q16 = qid & 15;
      ar[j] = *(const float4*)(Af + (size_t)(m0 + row) * K + k0 + q16 * 4);
    }
  };
  auto WRITE_A = [&]() {
#pragma unroll
    for (int j = 0; j < 8; ++j) {
      int qid = t + j * 256;
      int row = qid >> 4;
      int q16 = qid & 15;
      u32x2 w;
      w.x = cvt_pk_bf16(ar[j].x, ar[j].y);
      w.y = cvt_pk_bf16(ar[j].z, ar[j].w);
      int byte = (row * 128 + q16 * 8) ^ ((row & 7) << 4);
      *(u32x2*)(As + byte) = w;
    }
  };
  auto STAGE_B = [&](int k0, int s) {
#pragma unroll
    for (int j = 0; j < 4; ++j) {
      int p = (wv * 4 + j) * 1024 + lane * 16;
      int row = p >> 7;
      int cb = (p & 127) ^ ((row & 7) << 4);
      gload_lds16(Bw + (size_t)(n0 + row) * K + k0 + (cb >> 1),
                  Bs[s] + (wv * 4 + j) * 1024);
    }
  };

  LOAD_A(0);
  STAGE_B(0, 0);
  const int nk = K >> 6;  // 16
  for (int i = 0; i < nk; ++i) {
    const int s = i & 1;
    WRITE_A();  // tile i: compiler drains only the 8 A-loads (B DMA stays)
    if (i + 1 < nk) {
      LOAD_A((i + 1) << 6);
      STAGE_B((i + 1) << 6, s ^ 1);
      asm volatile("s_waitcnt vmcnt(12) lgkmcnt(0)" ::: "memory");
    } else {
      asm volatile("s_waitcnt vmcnt(0) lgkmcnt(0)" ::: "memory");
    }
    __builtin_amdgcn_s_barrier();  // tile i (As writes + B(i) DMA) visible

    bf16x8 af[2][4], bfr[2][4];
#pragma unroll
    for (int kh = 0; kh < 2; ++kh) {
#pragma unroll
      for (int m = 0; m < 4; ++m) {
        int r = wr * 64 + m * 16 + l15;
        int byte = (r * 128 + kh * 64 + l4 * 16) ^ ((r & 7) << 4);
        af[kh][m] = *(const bf16x8*)(As + byte);
      }
#pragma unroll
      for (int n = 0; n < 4; ++n) {
        int r = wc * 64 + n * 16 + l15;
        int byte = (r * 128 + kh * 64 + l4 * 16) ^ ((r & 7) << 4);
        bfr[kh][n] = *(const bf16x8*)(Bs[s] + byte);
      }
    }
#pragma unroll
    for (int kh = 0; kh < 2; ++kh)
#pragma unroll
      for (int m = 0; m < 4; ++m)
#pragma unroll
        for (int n = 0; n < 4; ++n)
          acc[m][n] = __builtin_amdgcn_mfma_f32_16x16x32_bf16(
              af[kh][m], bfr[kh][n], acc[m][n], 0, 0, 0);

    asm volatile("s_waitcnt lgkmcnt(0)" ::: "memory");  // own ds_reads retired
    __builtin_amdgcn_s_barrier();  // buffer-reuse fence (As, Bs[s^1])
  }

  if (which < 2) {
    unsigned short* Cp = dstQK + (size_t)which * 8388608;
#pragma unroll
    for (int n = 0; n < 4; ++n) {
      int col = n0 + wc * 64 + n * 16 + l15;
      float bc = bias[col];
#pragma unroll
      for (int m = 0; m < 4; ++m) {
        int rowb = m0 + wr * 64 + m * 16 + l4 * 4;
#pragma unroll
        for (int r = 0; r < 4; ++r) {
          float val = (acc[m][n][r] + bc) * osc;
          Cp[(size_t)(rowb + r) * N + col] = f2bf(val);
        }
      }
    }
  } else {
    // V: write transposed Vt[((b*16+h)*64+d)*2048 + s], 8B per (m,n)
#pragma unroll
    for (int n = 0; n < 4; ++n) {
      int dcol = n0 + wc * 64 + n * 16 + l15;  // h*64+d in 0..1023
      float bc = bias[dcol];
#pragma unroll
      for (int m = 0; m < 4; ++m) {
        int srow = m0 + wr * 64 + m * 16 + l4 * 4;  // b*2048+s, 4-aligned
        int bb = srow >> 11, s = srow & 2047;
        ushort4v o;
#pragma unroll
        for (int r = 0; r < 4; ++r) o[r] = f2bf(acc[m][n][r] + bc);
        *(ushort4v*)(Vt + ((size_t)(bb * 1024 + dcol)) * 2048 + s) = o;
      }
    }
  }
}

// ---------------- out GEMM (R12-R15 GREEN, byte-identical) -----------------
__launch_bounds__(256)
__global__ void gemm_out(const unsigned short* __restrict__ Ab,
                         const unsigned short* __restrict__ Bw,
                         const float* __restrict__ bias,
                         float* __restrict__ Cp, int M, int N, int K) {
  __shared__ __align__(16) unsigned char As[16384];
  __shared__ __align__(16) unsigned char Bs[16384];
  const int cpx = gridDim.x >> 3;
  const int bid = (blockIdx.x & 7) * cpx + (blockIdx.x >> 3);
  const int nb = N >> 7;
  const int bm = bid / nb, bn = bid % nb;
  const int m0 = bm << 7, n0 = bn << 7;
  const int t = threadIdx.x, lane = t & 63, wv = t >> 6;
  const int wr = wv >> 1, wc = wv & 1;
  const int l15 = lane & 15, l4 = lane >> 4;

  f32x4 acc[4][4] = {};

  for (int k0 = 0; k0 < K; k0 += 64) {
#pragma unroll
    for (int j = 0; j < 4; ++j) {
      int p = (wv * 4 + j) * 1024 + lane * 16;
      int row = p >> 7;
      int cb = (p & 127) ^ ((row & 7) << 4);
      gload_lds16(Bw + (size_t)(n0 + row) * K + k0 + (cb >> 1),
                  Bs + (wv * 4 + j) * 1024);
      gload_lds16(Ab + (size_t)(m0 + row) * K + k0 + (cb >> 1),
                  As + (wv * 4 + j) * 1024);
    }
    asm volatile("s_waitcnt vmcnt(0)" ::: "memory");
    __syncthreads();

    bf16x8 af[2][4], bfr[2][4];
#pragma unroll
    for (int kh = 0; kh < 2; ++kh) {
#pragma unroll
      for (int m = 0; m < 4; ++m) {
        int r = wr * 64 + m * 16 + l15;
        int byte = (r * 128 + kh * 64 + l4 * 16) ^ ((r & 7) << 4);
        af[kh][m] = *(const bf16x8*)(As + byte);
      }
#pragma unroll
      for (int n = 0; n < 4; ++n) {
        int r = wc * 64 + n * 16 + l15;
        int byte = (r * 128 + kh * 64 + l4 * 16) ^ ((r & 7) << 4);
        bfr[kh][n] = *(const bf16x8*)(Bs + byte);
      }
    }
#pragma unroll
    for (int kh = 0; kh < 2; ++kh)
#pragma unroll
      for (int m = 0; m < 4; ++m)
#pragma unroll
        for (int n = 0; n < 4; ++n)
          acc[m][n] = __builtin_amdgcn_mfma_f32_16x16x32_bf16(
              af[kh][m], bfr[kh][n], acc[m][n], 0, 0, 0);
    __syncthreads();
  }

#pragma unroll
  for (int n = 0; n < 4; ++n) {
    int col = n0 + wc * 64 + n * 16 + l15;
    float bc = bias[col];
#pragma unroll
    for (int m = 0; m < 4; ++m) {
      int rowb = m0 + wr * 64 + m * 16 + l4 * 4;
#pragma unroll
      for (int r = 0; r < 4; ++r)
        Cp[(size_t)(rowb + r) * N + col] = acc[m][n][r] + bc;
    }
  }
}

// ---------------- flash attention: V direct from L2 (FIXED), K LDS dbuf ----
// paired q-tiles, KVBLK=128; V read per-lane from Vt (element offsets
// k0 + kk*16 + hi*8 — R16's bug was byte offsets reused as elements).
__launch_bounds__(256)
__global__ void attn_kernel(const unsigned short* __restrict__ Qh,
                            const unsigned short* __restrict__ Kh,
                            const unsigned short* __restrict__ Vt,
                            const int* __restrict__ pad,
                            const int* __restrict__ pcausal,
                            unsigned short* __restrict__ Out) {
  __shared__ __align__(16) unsigned char Ks[2][16384];
  const int bid = (blockIdx.x & 7) * 64 + (blockIdx.x >> 3);  // XCD swizzle
  const int pr = bid & 7, h = (bid >> 3) & 15, b = bid >> 7;
  const int t = threadIdx.x, lane = t & 63, wv = t >> 6;
  const int l31 = lane & 31, hi = lane >> 5;
  const int causal = *pcausal;
  const unsigned short* Vbh = Vt + (size_t)(b * NH + h) * DH * SS;

  for (int half = 0; half < 2; ++half) {
    const int qt = half ? (15 - pr) : pr;
    const int q0 = qt << 7;
    const int qrow = q0 + wv * 32 + l31;  // this lane's q index
    const bool padded = (pad[b * SS + qrow] == 0);

    const unsigned short* Qb = Qh + ((size_t)(b * SS) + qrow) * HID + h * DH;
    bf16x8 qf[4];
#pragma unroll
    for (int dd = 0; dd < 4; ++dd) {
      qf[dd] = *(const bf16x8*)(Qb + dd * 16 + hi * 8);
      if (padded) qf[dd] = (bf16x8)0;
    }

    f32x16 oacc[2] = {};
    float m = -__builtin_inff(), l = 0.f;
    const int nkt = causal ? (qt + 1) : (SS >> 7);

    auto STAGE = [&](int kt, int s) {
#pragma unroll
      for (int j = 0; j < 4; ++j) {
        int p = (wv * 4 + j) * 1024 + lane * 16;
        int kr = p >> 7;
        int kcb = (p & 127) ^ ((kr & 7) << 4);
        gload_lds16(Kh + ((size_t)(b * SS) + (kt << 7) + kr) * HID + h * DH +
                        (kcb >> 1),
                    Ks[s] + (wv * 4 + j) * 1024);
      }
    };

    if (half) __syncthreads();  // protect K buffers from previous half's reads
    STAGE(0, 0);
    for (int kt = 0; kt < nkt; ++kt) {
      asm volatile("s_waitcnt vmcnt(0)" ::: "memory");  // own DMA drained
      __syncthreads();            // all waves' tile-kt DMA now visible
      if (kt + 1 < nkt) STAGE(kt + 1, (kt + 1) & 1);  // prefetch next
      const unsigned char* Kb = Ks[kt & 1];

#pragma unroll
      for (int sub = 0; sub < 2; ++sub) {
        const int k0 = (kt << 7) + (sub << 6);
        const bool active = (!causal) || (k0 <= q0 + wv * 32 + 31);
        if (!active) continue;
        // S^T = K * Q : out row = k, col = q
        f32x16 sacc[2] = {};
        __builtin_amdgcn_s_setprio(1);
#pragma unroll
        for (int kb = 0; kb < 2; ++kb) {
#pragma unroll
          for (int dd = 0; dd < 4; ++dd) {
            int krow = sub * 64 + kb * 32 + l31;
            int byte = (krow * 128 + dd * 32 + hi * 16) ^ ((krow & 7) << 4);
            bf16x8 kf = *(const bf16x8*)(Kb + byte);
            sacc[kb] = __builtin_amdgcn_mfma_f32_32x32x16_bf16(kf, qf[dd],
                                                               sacc[kb], 0, 0, 0);
          }
        }
        __builtin_amdgcn_s_setprio(0);
        // causal mask (diagonal sub-tiles only)
        if (causal && (k0 + 63 > q0 + wv * 32)) {
#pragma unroll
          for (int kb = 0; kb < 2; ++kb)
#pragma unroll
            for (int r = 0; r < 16; ++r) {
              int kidx = k0 + kb * 32 + (r & 3) + 8 * (r >> 2) + 4 * hi;
              if (kidx > qrow) sacc[kb][r] = -__builtin_inff();
            }
        }
        // row max (max3-fused tree) + partner exchange
        float ta = fmaxf(sacc[0][0], sacc[0][1]);
        float tb = fmaxf(sacc[0][2], sacc[0][3]);
#pragma unroll
        for (int r = 4; r < 16; r += 4) {
          ta = fmaxf(ta, fmaxf(sacc[0][r], sacc[0][r + 1]));
          tb = fmaxf(tb, fmaxf(sacc[0][r + 2], sacc[0][r + 3]));
        }
#pragma unroll
        for (int r = 0; r < 16; r += 4) {
          ta = fmaxf(ta, fmaxf(sacc[1][r], sacc[1][r + 1]));
          tb = fmaxf(tb, fmaxf(sacc[1][r + 2], sacc[1][r + 3]));
        }
        float tmax = fmaxf(ta, tb);
        tmax = fmaxf(tmax, __shfl_xor(tmax, 32));
        // defer-max: rescale only when wave-any growth > 8
        if (__any(tmax > m + 8.0f)) {
          float mnew = fmaxf(m, tmax);
          float corr = __builtin_amdgcn_exp2f(m - mnew);
          m = mnew;
          l *= corr;
#pragma unroll
          for (int db = 0; db < 2; ++db)
#pragma unroll
            for (int r = 0; r < 16; ++r) oacc[db][r] *= corr;
        }
        float ls = 0.f;
#pragma unroll
        for (int kb = 0; kb < 2; ++kb)
#pragma unroll
          for (int r = 0; r < 16; ++r) {
            float p = __builtin_amdgcn_exp2f(sacc[kb][r] - m);
            sacc[kb][r] = p;
            ls += p;
          }
        l += ls;

        // pack P^T into PV B-fragments
        bf16x8 pf[4];
#pragma unroll
        for (int kb = 0; kb < 2; ++kb) {
          unsigned w0 = cvt_pk_bf16(sacc[kb][0], sacc[kb][1]);
          unsigned w1 = cvt_pk_bf16(sacc[kb][2], sacc[kb][3]);
          unsigned w2 = cvt_pk_bf16(sacc[kb][4], sacc[kb][5]);
          unsigned w3 = cvt_pk_bf16(sacc[kb][6], sacc[kb][7]);
          unsigned w4 = cvt_pk_bf16(sacc[kb][8], sacc[kb][9]);
          unsigned w5 = cvt_pk_bf16(sacc[kb][10], sacc[kb][11]);
          unsigned w6 = cvt_pk_bf16(sacc[kb][12], sacc[kb][13]);
          unsigned w7 = cvt_pk_bf16(sacc[kb][14], sacc[kb][15]);
          unsigned t0 = __shfl_xor(hi ? w0 : w2, 32);
          unsigned t1 = __shfl_xor(hi ? w1 : w3, 32);
          unsigned t2 = __shfl_xor(hi ? w4 : w6, 32);
          unsigned t3 = __shfl_xor(hi ? w5 : w7, 32);
          u32x4 lo, hf;
          lo[0] = hi ? t0 : w0;
          lo[1] = hi ? t1 : w1;
          lo[2] = hi ? w2 : t0;
          lo[3] = hi ? w3 : t1;
          hf[0] = hi ? t2 : w4;
          hf[1] = hi ? t3 : w5;
          hf[2] = hi ? w6 : t2;
          hf[3] = hi ? w7 : t3;
          pf[2 * kb] = __builtin_bit_cast(bf16x8, lo);
          pf[2 * kb + 1] = __builtin_bit_cast(bf16x8, hf);
        }
        // O^T += V^T * P^T ; V A-frags from global (L2-resident).
        // Element offsets: row=drow, k = k0 + kk*16 + hi*8 (16B loads).
        __builtin_amdgcn_s_setprio(1);
#pragma unroll
        for (int db = 0; db < 2; ++db) {
          int drow = db * 32 + l31;
          const unsigned short* vr = Vbh + (size_t)drow * SS + k0 + hi * 8;
#pragma unroll
          for (int kk = 0; kk < 4; ++kk) {
            bf16x8 vf = *(const bf16x8*)(vr + kk * 16);
            oacc[db] = __builtin_amdgcn_mfma_f32_32x32x16_bf16(vf, pf[kk],
                                                               oacc[db], 0, 0, 0);
          }
        }
        __builtin_amdgcn_s_setprio(0);
      }
    }

    float ltot = l + __shfl_xor(l, 32);
    float inv = 1.0f / ltot;
    size_t rowoff = ((size_t)(b * SS) + qrow) * HID + h * DH;
#pragma unroll
    for (int db = 0; db < 2; ++db) {
#pragma unroll
      for (int g = 0; g < 4; ++g) {
        ushort4v o;
#pragma unroll
        for (int j = 0; j < 4; ++j) o[j] = f2bf(oacc[db][4 * g + j] * inv);
        *(ushort4v*)(Out + rowoff + db * 32 + 8 * g + 4 * hi) = o;
      }
    }
  }
}

// ---------------- launch ----------------
extern "C" void kernel_launch(void* const* d_in, const int* in_sizes, int n_in,
                              void* d_out, int out_size, void* d_ws,
                              size_t ws_size, hipStream_t stream) {
  const float* q = (const float*)d_in[0];
  const float* k = (const float*)d_in[1];
  const float* v = (const float*)d_in[2];
  const int* pad = (const int*)d_in[3];
  const float* Wq = (const float*)d_in[4];
  const float* bq = (const float*)d_in[5];
  const float* Wk = (const float*)d_in[6];
  const float* bk = (const float*)d_in[7];
  const float* Wv = (const float*)d_in[8];
  const float* bv = (const float*)d_in[9];
  const float* Wo = (const float*)d_in[10];
  const float* bo = (const float*)d_in[11];
  const int* iscausal = (const int*)d_in[12];
  float* out = (float*)d_out;

  const float SCL = 0.18033688011112042f;  // (1/8) * log2(e)
  const int NQKV = BB * SS * HID;          // 8388608

  // ws (ushorts): Wcat 4x1M | Qh | Kh | Vt | Htmp   (75.5 MB)
  unsigned short* Wcat = (unsigned short*)d_ws;
  unsigned short* Wob = Wcat + 3145728;
  unsigned short* Qh = Wob + 1048576;
  unsigned short* Kh = Qh + (size_t)NQKV;
  unsigned short* Vtp = Kh + (size_t)NQKV;
  unsigned short* Htmp = Vtp + (size_t)NQKV;

  cvt4_weights<<<4096, 256, 0, stream>>>(Wq, Wk, Wv, Wo, Wcat);

  gemm_qkv<<<1536, 256, 0, stream>>>(q, k, v, Wcat, bq, bk, bv, Qh, Vtp, SCL);

  attn_kernel<<<512, 256, 0, stream>>>(Qh, Kh, Vtp, pad, iscausal, Htmp);

  gemm_out<<<512, 256, 0, stream>>>(Htmp, Wob, bo, out, 8192, 1024, 1024);
}

// Round 18
// 178.927 us; speedup vs baseline: 1.1454x; 1.1454x over previous
//
#include <hip/hip_runtime.h>
#include <hip/hip_bf16.h>
#include <stdint.h>

typedef __attribute__((ext_vector_type(8))) short bf16x8;
typedef __attribute__((ext_vector_type(4))) float f32x4;
typedef __attribute__((ext_vector_type(16))) float f32x16;
typedef __attribute__((ext_vector_type(8))) unsigned short ushort8;
typedef __attribute__((ext_vector_type(4))) unsigned short ushort4v;
typedef __attribute__((ext_vector_type(4))) unsigned int u32x4;
typedef __attribute__((ext_vector_type(2))) unsigned int u32x2;

#define DEVINL __device__ __forceinline__

static constexpr int BB  = 4;
static constexpr int SS  = 2048;
static constexpr int HID = 1024;
static constexpr int NH  = 16;
static constexpr int DH  = 64;

DEVINL unsigned short f2bf(float f) {
  unsigned u = __builtin_bit_cast(unsigned, f);
  u += 0x7fffu + ((u >> 16) & 1u);   // RNE
  return (unsigned short)(u >> 16);
}

DEVINL unsigned cvt_pk_bf16(float lo, float hi) {
  unsigned r;
  asm("v_cvt_pk_bf16_f32 %0, %1, %2" : "=v"(r) : "v"(lo), "v"(hi));
  return r;
}

DEVINL void gload_lds16(const void* g, void* lds) {
  __builtin_amdgcn_global_load_lds(
      (__attribute__((address_space(1))) unsigned int*)(g),
      (__attribute__((address_space(3))) unsigned int*)(lds), 16, 0, 0);
}

// all 4 weight matrices in one launch; dst = [4][1M] (Wq,Wk,Wv,Wo)
__global__ void cvt4_weights(const float* __restrict__ a,
                             const float* __restrict__ b,
                             const float* __restrict__ c,
                             const float* __restrict__ d,
                             unsigned short* __restrict__ dst) {
  int which = blockIdx.x >> 10;
  const float* src = which == 0 ? a : which == 1 ? b : which == 2 ? c : d;
  int i = ((blockIdx.x & 1023) * 256 + threadIdx.x) * 4;
  float4 v = *(const float4*)(src + i);
  ushort4v h;
  h.x = f2bf(v.x); h.y = f2bf(v.y); h.z = f2bf(v.z); h.w = f2bf(v.w);
  *(ushort4v*)(dst + which * 1048576 + i) = h;
}

// ---------------- grouped QKV GEMM, T4 counted-vmcnt (R15 GREEN) -----------
__launch_bounds__(256)
__global__ void gemm_qkv(const float* __restrict__ qp,
                         const float* __restrict__ kp,
                         const float* __restrict__ vp,
                         const unsigned short* __restrict__ W,
                         const float* __restrict__ bq,
                         const float* __restrict__ bk,
                         const float* __restrict__ bv,
                         unsigned short* __restrict__ dstQK,
                         unsigned short* __restrict__ Vt, float sclq) {
  __shared__ __align__(16) unsigned char As[16384];
  __shared__ __align__(16) unsigned char Bs[2][16384];
  const int cpx = gridDim.x >> 3;
  const int bid = (blockIdx.x & 7) * cpx + (blockIdx.x >> 3);
  const int which = bid / 512;
  const int tile = bid - which * 512;
  const int bm = tile >> 3, bn = tile & 7;
  const int m0 = bm << 7, n0 = bn << 7;
  const int K = 1024, N = 1024;
  const float* Af = which == 0 ? qp : which == 1 ? kp : vp;
  const unsigned short* Bw = W + which * 1048576;
  const float* bias = which == 0 ? bq : which == 1 ? bk : bv;
  const float osc = which == 0 ? sclq : 1.0f;

  const int t = threadIdx.x, lane = t & 63, wv = t >> 6;
  const int wr = wv >> 1, wc = wv & 1;
  const int l15 = lane & 15, l4 = lane >> 4;

  f32x4 acc[4][4] = {};
  float4 ar[8];  // A fp32 prefetch (one K-step ahead)

  auto LOAD_A = [&](int k0) {
#pragma unroll
    for (int j = 0; j < 8; ++j) {
      int qid = t + j * 256;
      int row = qid >> 4;
      int q16 = qid & 15;
      ar[j] = *(const float4*)(Af + (size_t)(m0 + row) * K + k0 + q16 * 4);
    }
  };
  auto WRITE_A = [&]() {
#pragma unroll
    for (int j = 0; j < 8; ++j) {
      int qid = t + j * 256;
      int row = qid >> 4;
      int q16 = qid & 15;
      u32x2 w;
      w.x = cvt_pk_bf16(ar[j].x, ar[j].y);
      w.y = cvt_pk_bf16(ar[j].z, ar[j].w);
      int byte = (row * 128 + q16 * 8) ^ ((row & 7) << 4);
      *(u32x2*)(As + byte) = w;
    }
  };
  auto STAGE_B = [&](int k0, int s) {
#pragma unroll
    for (int j = 0; j < 4; ++j) {
      int p = (wv * 4 + j) * 1024 + lane * 16;
      int row = p >> 7;
      int cb = (p & 127) ^ ((row & 7) << 4);
      gload_lds16(Bw + (size_t)(n0 + row) * K + k0 + (cb >> 1),
                  Bs[s] + (wv * 4 + j) * 1024);
    }
  };

  LOAD_A(0);
  STAGE_B(0, 0);
  const int nk = K >> 6;  // 16
  for (int i = 0; i < nk; ++i) {
    const int s = i & 1;
    WRITE_A();  // tile i: compiler drains only the 8 A-loads (B DMA stays)
    if (i + 1 < nk) {
      LOAD_A((i + 1) << 6);
      STAGE_B((i + 1) << 6, s ^ 1);
      asm volatile("s_waitcnt vmcnt(12) lgkmcnt(0)" ::: "memory");
    } else {
      asm volatile("s_waitcnt vmcnt(0) lgkmcnt(0)" ::: "memory");
    }
    __builtin_amdgcn_s_barrier();  // tile i (As writes + B(i) DMA) visible

    bf16x8 af[2][4], bfr[2][4];
#pragma unroll
    for (int kh = 0; kh < 2; ++kh) {
#pragma unroll
      for (int m = 0; m < 4; ++m) {
        int r = wr * 64 + m * 16 + l15;
        int byte = (r * 128 + kh * 64 + l4 * 16) ^ ((r & 7) << 4);
        af[kh][m] = *(const bf16x8*)(As + byte);
      }
#pragma unroll
      for (int n = 0; n < 4; ++n) {
        int r = wc * 64 + n * 16 + l15;
        int byte = (r * 128 + kh * 64 + l4 * 16) ^ ((r & 7) << 4);
        bfr[kh][n] = *(const bf16x8*)(Bs[s] + byte);
      }
    }
#pragma unroll
    for (int kh = 0; kh < 2; ++kh)
#pragma unroll
      for (int m = 0; m < 4; ++m)
#pragma unroll
        for (int n = 0; n < 4; ++n)
          acc[m][n] = __builtin_amdgcn_mfma_f32_16x16x32_bf16(
              af[kh][m], bfr[kh][n], acc[m][n], 0, 0, 0);

    asm volatile("s_waitcnt lgkmcnt(0)" ::: "memory");  // own ds_reads retired
    __builtin_amdgcn_s_barrier();  // buffer-reuse fence (As, Bs[s^1])
  }

  if (which < 2) {
    unsigned short* Cp = dstQK + (size_t)which * 8388608;
#pragma unroll
    for (int n = 0; n < 4; ++n) {
      int col = n0 + wc * 64 + n * 16 + l15;
      float bc = bias[col];
#pragma unroll
      for (int m = 0; m < 4; ++m) {
        int rowb = m0 + wr * 64 + m * 16 + l4 * 4;
#pragma unroll
        for (int r = 0; r < 4; ++r) {
          float val = (acc[m][n][r] + bc) * osc;
          Cp[(size_t)(rowb + r) * N + col] = f2bf(val);
        }
      }
    }
  } else {
    // V: write transposed Vt[((b*16+h)*64+d)*2048 + s], 8B per (m,n)
#pragma unroll
    for (int n = 0; n < 4; ++n) {
      int dcol = n0 + wc * 64 + n * 16 + l15;  // h*64+d in 0..1023
      float bc = bias[dcol];
#pragma unroll
      for (int m = 0; m < 4; ++m) {
        int srow = m0 + wr * 64 + m * 16 + l4 * 4;  // b*2048+s, 4-aligned
        int bb = srow >> 11, s = srow & 2047;
        ushort4v o;
#pragma unroll
        for (int r = 0; r < 4; ++r) o[r] = f2bf(acc[m][n][r] + bc);
        *(ushort4v*)(Vt + ((size_t)(bb * 1024 + dcol)) * 2048 + s) = o;
      }
    }
  }
}

// ---------------- out GEMM: counted-vmcnt dbuf pipeline (new) --------------
// Both A (bf16) and B staged via global_load_lds, double-buffered.
// Per tile: issue next 8 DMA, vmcnt(8) drains exactly tile-i's 8,
// raw barrier, compute, lgkm drain + barrier (buffer-reuse fence).
// LDS 64KB -> 2 blocks/CU = grid-imposed occupancy anyway (512 blocks).
__launch_bounds__(256)
__global__ void gemm_out(const unsigned short* __restrict__ Ab,
                         const unsigned short* __restrict__ Bw,
                         const float* __restrict__ bias,
                         float* __restrict__ Cp, int M, int N, int K) {
  __shared__ __align__(16) unsigned char As[2][16384];
  __shared__ __align__(16) unsigned char Bs[2][16384];
  const int cpx = gridDim.x >> 3;
  const int bid = (blockIdx.x & 7) * cpx + (blockIdx.x >> 3);
  const int nb = N >> 7;
  const int bm = bid / nb, bn = bid % nb;
  const int m0 = bm << 7, n0 = bn << 7;
  const int t = threadIdx.x, lane = t & 63, wv = t >> 6;
  const int wr = wv >> 1, wc = wv & 1;
  const int l15 = lane & 15, l4 = lane >> 4;

  f32x4 acc[4][4] = {};

  auto STAGE = [&](int k0, int s) {
#pragma unroll
    for (int j = 0; j < 4; ++j) {
      int p = (wv * 4 + j) * 1024 + lane * 16;
      int row = p >> 7;
      int cb = (p & 127) ^ ((row & 7) << 4);
      gload_lds16(Bw + (size_t)(n0 + row) * K + k0 + (cb >> 1),
                  Bs[s] + (wv * 4 + j) * 1024);
      gload_lds16(Ab + (size_t)(m0 + row) * K + k0 + (cb >> 1),
                  As[s] + (wv * 4 + j) * 1024);
    }
  };

  STAGE(0, 0);
  const int nk = K >> 6;
  for (int i = 0; i < nk; ++i) {
    const int s = i & 1;
    if (i + 1 < nk) {
      STAGE((i + 1) << 6, s ^ 1);
      // outstanding: [tile-i x8 oldest | tile-(i+1) x8]
      asm volatile("s_waitcnt vmcnt(8)" ::: "memory");
    } else {
      asm volatile("s_waitcnt vmcnt(0)" ::: "memory");
    }
    __builtin_amdgcn_s_barrier();  // tile i DMA visible to all waves

    bf16x8 af[2][4], bfr[2][4];
#pragma unroll
    for (int kh = 0; kh < 2; ++kh) {
#pragma unroll
      for (int m = 0; m < 4; ++m) {
        int r = wr * 64 + m * 16 + l15;
        int byte = (r * 128 + kh * 64 + l4 * 16) ^ ((r & 7) << 4);
        af[kh][m] = *(const bf16x8*)(As[s] + byte);
      }
#pragma unroll
      for (int n = 0; n < 4; ++n) {
        int r = wc * 64 + n * 16 + l15;
        int byte = (r * 128 + kh * 64 + l4 * 16) ^ ((r & 7) << 4);
        bfr[kh][n] = *(const bf16x8*)(Bs[s] + byte);
      }
    }
#pragma unroll
    for (int kh = 0; kh < 2; ++kh)
#pragma unroll
      for (int m = 0; m < 4; ++m)
#pragma unroll
        for (int n = 0; n < 4; ++n)
          acc[m][n] = __builtin_amdgcn_mfma_f32_16x16x32_bf16(
              af[kh][m], bfr[kh][n], acc[m][n], 0, 0, 0);

    asm volatile("s_waitcnt lgkmcnt(0)" ::: "memory");  // own ds_reads retired
    __builtin_amdgcn_s_barrier();  // buffer-reuse fence
  }

#pragma unroll
  for (int n = 0; n < 4; ++n) {
    int col = n0 + wc * 64 + n * 16 + l15;
    float bc = bias[col];
#pragma unroll
    for (int m = 0; m < 4; ++m) {
      int rowb = m0 + wr * 64 + m * 16 + l4 * 4;
#pragma unroll
      for (int r = 0; r < 4; ++r)
        Cp[(size_t)(rowb + r) * N + col] = acc[m][n][r] + bc;
    }
  }
}

// ---------------- flash attention (R12-R15 GREEN, byte-identical) ---------
// paired q-tiles, KVBLK=128 (2 subs per barrier), 2-phase dbuf + drain.
__launch_bounds__(256)
__global__ void attn_kernel(const unsigned short* __restrict__ Qh,
                            const unsigned short* __restrict__ Kh,
                            const unsigned short* __restrict__ Vt,
                            const int* __restrict__ pad,
                            const int* __restrict__ pcausal,
                            unsigned short* __restrict__ Out) {
  __shared__ __align__(16) unsigned char Ks[2][16384];
  __shared__ __align__(16) unsigned char Vs[2][16384];
  const int bid = (blockIdx.x & 7) * 64 + (blockIdx.x >> 3);  // XCD swizzle
  const int pr = bid & 7, h = (bid >> 3) & 15, b = bid >> 7;
  const int t = threadIdx.x, lane = t & 63, wv = t >> 6;
  const int l31 = lane & 31, hi = lane >> 5;
  const int causal = *pcausal;

  for (int half = 0; half < 2; ++half) {
    const int qt = half ? (15 - pr) : pr;
    const int q0 = qt << 7;
    const int qrow = q0 + wv * 32 + l31;  // this lane's q index
    const bool padded = (pad[b * SS + qrow] == 0);

    const unsigned short* Qb = Qh + ((size_t)(b * SS) + qrow) * HID + h * DH;
    bf16x8 qf[4];
#pragma unroll
    for (int dd = 0; dd < 4; ++dd) {
      qf[dd] = *(const bf16x8*)(Qb + dd * 16 + hi * 8);
      if (padded) qf[dd] = (bf16x8)0;
    }

    f32x16 oacc[2] = {};
    float m = -__builtin_inff(), l = 0.f;
    const int nkt = causal ? (qt + 1) : (SS >> 7);

    auto STAGE = [&](int kt, int s) {
#pragma unroll
      for (int j = 0; j < 4; ++j) {
        int p = (wv * 4 + j) * 1024 + lane * 16;
        int kr = p >> 7;
        int kcb = (p & 127) ^ ((kr & 7) << 4);
        gload_lds16(Kh + ((size_t)(b * SS) + (kt << 7) + kr) * HID + h * DH +
                        (kcb >> 1),
                    Ks[s] + (wv * 4 + j) * 1024);
        int vr = p >> 8;
        int vcb = (p & 255) ^ ((vr & 15) << 4);
        gload_lds16(Vt + ((size_t)((b * NH + h) * DH + vr)) * SS + (kt << 7) +
                        (vcb >> 1),
                    Vs[s] + (wv * 4 + j) * 1024);
      }
    };

    if (half) __syncthreads();  // protect buffers from previous half's reads
    STAGE(0, 0);
    for (int kt = 0; kt < nkt; ++kt) {
      asm volatile("s_waitcnt vmcnt(0)" ::: "memory");  // own DMA drained
      __syncthreads();            // all waves' tile-kt DMA now visible
      if (kt + 1 < nkt) STAGE(kt + 1, (kt + 1) & 1);  // prefetch next
      const unsigned char* Kb = Ks[kt & 1];
      const unsigned char* Vb = Vs[kt & 1];

#pragma unroll
      for (int sub = 0; sub < 2; ++sub) {
        const int k0 = (kt << 7) + (sub << 6);
        const bool active = (!causal) || (k0 <= q0 + wv * 32 + 31);
        if (!active) continue;
        // S^T = K * Q : out row = k, col = q
        f32x16 sacc[2] = {};
#pragma unroll
        for (int kb = 0; kb < 2; ++kb) {
#pragma unroll
          for (int dd = 0; dd < 4; ++dd) {
            int krow = sub * 64 + kb * 32 + l31;
            int byte = (krow * 128 + dd * 32 + hi * 16) ^ ((krow & 7) << 4);
            bf16x8 kf = *(const bf16x8*)(Kb + byte);
            sacc[kb] = __builtin_amdgcn_mfma_f32_32x32x16_bf16(kf, qf[dd],
                                                               sacc[kb], 0, 0, 0);
          }
        }
        // causal mask (diagonal sub-tiles only)
        if (causal && (k0 + 63 > q0 + wv * 32)) {
#pragma unroll
          for (int kb = 0; kb < 2; ++kb)
#pragma unroll
            for (int r = 0; r < 16; ++r) {
              int kidx = k0 + kb * 32 + (r & 3) + 8 * (r >> 2) + 4 * hi;
              if (kidx > qrow) sacc[kb][r] = -__builtin_inff();
            }
        }
        // row max (max3-fused tree) + partner exchange
        float ta = fmaxf(sacc[0][0], sacc[0][1]);
        float tb = fmaxf(sacc[0][2], sacc[0][3]);
#pragma unroll
        for (int r = 4; r < 16; r += 4) {
          ta = fmaxf(ta, fmaxf(sacc[0][r], sacc[0][r + 1]));
          tb = fmaxf(tb, fmaxf(sacc[0][r + 2], sacc[0][r + 3]));
        }
#pragma unroll
        for (int r = 0; r < 16; r += 4) {
          ta = fmaxf(ta, fmaxf(sacc[1][r], sacc[1][r + 1]));
          tb = fmaxf(tb, fmaxf(sacc[1][r + 2], sacc[1][r + 3]));
        }
        float tmax = fmaxf(ta, tb);
        tmax = fmaxf(tmax, __shfl_xor(tmax, 32));
        // defer-max: rescale only when wave-any growth > 8
        if (__any(tmax > m + 8.0f)) {
          float mnew = fmaxf(m, tmax);
          float corr = __builtin_amdgcn_exp2f(m - mnew);
          m = mnew;
          l *= corr;
#pragma unroll
          for (int db = 0; db < 2; ++db)
#pragma unroll
            for (int r = 0; r < 16; ++r) oacc[db][r] *= corr;
        }
        float ls = 0.f;
#pragma unroll
        for (int kb = 0; kb < 2; ++kb)
#pragma unroll
          for (int r = 0; r < 16; ++r) {
            float p = __builtin_amdgcn_exp2f(sacc[kb][r] - m);
            sacc[kb][r] = p;
            ls += p;
          }
        l += ls;

        // pack P^T into PV B-fragments
        bf16x8 pf[4];
#pragma unroll
        for (int kb = 0; kb < 2; ++kb) {
          unsigned w0 = cvt_pk_bf16(sacc[kb][0], sacc[kb][1]);
          unsigned w1 = cvt_pk_bf16(sacc[kb][2], sacc[kb][3]);
          unsigned w2 = cvt_pk_bf16(sacc[kb][4], sacc[kb][5]);
          unsigned w3 = cvt_pk_bf16(sacc[kb][6], sacc[kb][7]);
          unsigned w4 = cvt_pk_bf16(sacc[kb][8], sacc[kb][9]);
          unsigned w5 = cvt_pk_bf16(sacc[kb][10], sacc[kb][11]);
          unsigned w6 = cvt_pk_bf16(sacc[kb][12], sacc[kb][13]);
          unsigned w7 = cvt_pk_bf16(sacc[kb][14], sacc[kb][15]);
          unsigned t0 = __shfl_xor(hi ? w0 : w2, 32);
          unsigned t1 = __shfl_xor(hi ? w1 : w3, 32);
          unsigned t2 = __shfl_xor(hi ? w4 : w6, 32);
          unsigned t3 = __shfl_xor(hi ? w5 : w7, 32);
          u32x4 lo, hf;
          lo[0] = hi ? t0 : w0;
          lo[1] = hi ? t1 : w1;
          lo[2] = hi ? w2 : t0;
          lo[3] = hi ? w3 : t1;
          hf[0] = hi ? t2 : w4;
          hf[1] = hi ? t3 : w5;
          hf[2] = hi ? w6 : t2;
          hf[3] = hi ? w7 : t3;
          pf[2 * kb] = __builtin_bit_cast(bf16x8, lo);
          pf[2 * kb + 1] = __builtin_bit_cast(bf16x8, hf);
        }
        // O^T += V^T * P^T   (V rows 256B, sub selects 128B half)
#pragma unroll
        for (int db = 0; db < 2; ++db) {
#pragma unroll
          for (int kk = 0; kk < 4; ++kk) {
            int drow = db * 32 + l31;
            int byte = (drow * 256 + sub * 128 + kk * 32 + hi * 16) ^
                       ((drow & 15) << 4);
            bf16x8 vf = *(const bf16x8*)(Vb + byte);
            oacc[db] = __builtin_amdgcn_mfma_f32_32x32x16_bf16(vf, pf[kk],
                                                               oacc[db], 0, 0, 0);
          }
        }
      }
    }

    float ltot = l + __shfl_xor(l, 32);
    float inv = 1.0f / ltot;
    size_t rowoff = ((size_t)(b * SS) + qrow) * HID + h * DH;
#pragma unroll
    for (int db = 0; db < 2; ++db) {
#pragma unroll
      for (int g = 0; g < 4; ++g) {
        ushort4v o;
#pragma unroll
        for (int j = 0; j < 4; ++j) o[j] = f2bf(oacc[db][4 * g + j] * inv);
        *(ushort4v*)(Out + rowoff + db * 32 + 8 * g + 4 * hi) = o;
      }
    }
  }
}

// ---------------- launch ----------------
extern "C" void kernel_launch(void* const* d_in, const int* in_sizes, int n_in,
                              void* d_out, int out_size, void* d_ws,
                              size_t ws_size, hipStream_t stream) {
  const float* q = (const float*)d_in[0];
  const float* k = (const float*)d_in[1];
  const float* v = (const float*)d_in[2];
  const int* pad = (const int*)d_in[3];
  const float* Wq = (const float*)d_in[4];
  const float* bq = (const float*)d_in[5];
  const float* Wk = (const float*)d_in[6];
  const float* bk = (const float*)d_in[7];
  const float* Wv = (const float*)d_in[8];
  const float* bv = (const float*)d_in[9];
  const float* Wo = (const float*)d_in[10];
  const float* bo = (const float*)d_in[11];
  const int* iscausal = (const int*)d_in[12];
  float* out = (float*)d_out;

  const float SCL = 0.18033688011112042f;  // (1/8) * log2(e)
  const int NQKV = BB * SS * HID;          // 8388608

  // ws (ushorts): Wcat 4x1M | Qh | Kh | Vt | Htmp   (75.5 MB)
  unsigned short* Wcat = (unsigned short*)d_ws;
  unsigned short* Wob = Wcat + 3145728;
  unsigned short* Qh = Wob + 1048576;
  unsigned short* Kh = Qh + (size_t)NQKV;
  unsigned short* Vtp = Kh + (size_t)NQKV;
  unsigned short* Htmp = Vtp + (size_t)NQKV;

  cvt4_weights<<<4096, 256, 0, stream>>>(Wq, Wk, Wv, Wo, Wcat);

  gemm_qkv<<<1536, 256, 0, stream>>>(q, k, v, Wcat, bq, bk, bv, Qh, Vtp, SCL);

  attn_kernel<<<512, 256, 0, stream>>>(Qh, Kh, Vtp, pad, iscausal, Htmp);

  gemm_out<<<512, 256, 0, stream>>>(Htmp, Wob, bo, out, 8192, 1024, 1024);
}

// Round 19
// 178.713 us; speedup vs baseline: 1.1468x; 1.0012x over previous
//
#include <hip/hip_runtime.h>
#include <hip/hip_bf16.h>
#include <stdint.h>

typedef __attribute__((ext_vector_type(8))) short bf16x8;
typedef __attribute__((ext_vector_type(4))) float f32x4;
typedef __attribute__((ext_vector_type(16))) float f32x16;
typedef __attribute__((ext_vector_type(8))) unsigned short ushort8;
typedef __attribute__((ext_vector_type(4))) unsigned short ushort4v;
typedef __attribute__((ext_vector_type(4))) unsigned int u32x4;
typedef __attribute__((ext_vector_type(2))) unsigned int u32x2;

#define DEVINL __device__ __forceinline__

static constexpr int BB  = 4;
static constexpr int SS  = 2048;
static constexpr int HID = 1024;
static constexpr int NH  = 16;
static constexpr int DH  = 64;

DEVINL unsigned short f2bf(float f) {
  unsigned u = __builtin_bit_cast(unsigned, f);
  u += 0x7fffu + ((u >> 16) & 1u);   // RNE
  return (unsigned short)(u >> 16);
}

DEVINL unsigned cvt_pk_bf16(float lo, float hi) {
  unsigned r;
  asm("v_cvt_pk_bf16_f32 %0, %1, %2" : "=v"(r) : "v"(lo), "v"(hi));
  return r;
}

DEVINL void gload_lds16(const void* g, void* lds) {
  __builtin_amdgcn_global_load_lds(
      (__attribute__((address_space(1))) unsigned int*)(g),
      (__attribute__((address_space(3))) unsigned int*)(lds), 16, 0, 0);
}

// all 4 weight matrices; 8 elems/thread, 16B stores. dst = [4][1M]
__global__ void cvt4_weights(const float* __restrict__ a,
                             const float* __restrict__ b,
                             const float* __restrict__ c,
                             const float* __restrict__ d,
                             unsigned short* __restrict__ dst) {
  int which = blockIdx.x >> 9;
  const float* src = which == 0 ? a : which == 1 ? b : which == 2 ? c : d;
  int i = ((blockIdx.x & 511) * 256 + threadIdx.x) * 8;
  float4 v0 = *(const float4*)(src + i);
  float4 v1 = *(const float4*)(src + i + 4);
  ushort8 h;
  h[0] = f2bf(v0.x); h[1] = f2bf(v0.y); h[2] = f2bf(v0.z); h[3] = f2bf(v0.w);
  h[4] = f2bf(v1.x); h[5] = f2bf(v1.y); h[6] = f2bf(v1.z); h[7] = f2bf(v1.w);
  *(ushort8*)(dst + which * 1048576 + i) = h;
}

// ---------------- grouped QKV GEMM, T4 counted-vmcnt (R15/R18 GREEN) -------
__launch_bounds__(256)
__global__ void gemm_qkv(const float* __restrict__ qp,
                         const float* __restrict__ kp,
                         const float* __restrict__ vp,
                         const unsigned short* __restrict__ W,
                         const float* __restrict__ bq,
                         const float* __restrict__ bk,
                         const float* __restrict__ bv,
                         unsigned short* __restrict__ dstQK,
                         unsigned short* __restrict__ Vt, float sclq) {
  __shared__ __align__(16) unsigned char As[16384];
  __shared__ __align__(16) unsigned char Bs[2][16384];
  const int cpx = gridDim.x >> 3;
  const int bid = (blockIdx.x & 7) * cpx + (blockIdx.x >> 3);
  const int which = bid / 512;
  const int tile = bid - which * 512;
  const int bm = tile >> 3, bn = tile & 7;
  const int m0 = bm << 7, n0 = bn << 7;
  const int K = 1024, N = 1024;
  const float* Af = which == 0 ? qp : which == 1 ? kp : vp;
  const unsigned short* Bw = W + which * 1048576;
  const float* bias = which == 0 ? bq : which == 1 ? bk : bv;
  const float osc = which == 0 ? sclq : 1.0f;

  const int t = threadIdx.x, lane = t & 63, wv = t >> 6;
  const int wr = wv >> 1, wc = wv & 1;
  const int l15 = lane & 15, l4 = lane >> 4;

  f32x4 acc[4][4] = {};
  float4 ar[8];  // A fp32 prefetch (one K-step ahead)

  auto LOAD_A = [&](int k0) {
#pragma unroll
    for (int j = 0; j < 8; ++j) {
      int qid = t + j * 256;
      int row = qid >> 4;
      int q16 = qid & 15;
      ar[j] = *(const float4*)(Af + (size_t)(m0 + row) * K + k0 + q16 * 4);
    }
  };
  auto WRITE_A = [&]() {
#pragma unroll
    for (int j = 0; j < 8; ++j) {
      int qid = t + j * 256;
      int row = qid >> 4;
      int q16 = qid & 15;
      u32x2 w;
      w.x = cvt_pk_bf16(ar[j].x, ar[j].y);
      w.y = cvt_pk_bf16(ar[j].z, ar[j].w);
      int byte = (row * 128 + q16 * 8) ^ ((row & 7) << 4);
      *(u32x2*)(As + byte) = w;
    }
  };
  auto STAGE_B = [&](int k0, int s) {
#pragma unroll
    for (int j = 0; j < 4; ++j) {
      int p = (wv * 4 + j) * 1024 + lane * 16;
      int row = p >> 7;
      int cb = (p & 127) ^ ((row & 7) << 4);
      gload_lds16(Bw + (size_t)(n0 + row) * K + k0 + (cb >> 1),
                  Bs[s] + (wv * 4 + j) * 1024);
    }
  };

  LOAD_A(0);
  STAGE_B(0, 0);
  const int nk = K >> 6;  // 16
  for (int i = 0; i < nk; ++i) {
    const int s = i & 1;
    WRITE_A();  // tile i: compiler drains only the 8 A-loads (B DMA stays)
    if (i + 1 < nk) {
      LOAD_A((i + 1) << 6);
      STAGE_B((i + 1) << 6, s ^ 1);
      asm volatile("s_waitcnt vmcnt(12) lgkmcnt(0)" ::: "memory");
    } else {
      asm volatile("s_waitcnt vmcnt(0) lgkmcnt(0)" ::: "memory");
    }
    __builtin_amdgcn_s_barrier();  // tile i (As writes + B(i) DMA) visible

    bf16x8 af[2][4], bfr[2][4];
#pragma unroll
    for (int kh = 0; kh < 2; ++kh) {
#pragma unroll
      for (int m = 0; m < 4; ++m) {
        int r = wr * 64 + m * 16 + l15;
        int byte = (r * 128 + kh * 64 + l4 * 16) ^ ((r & 7) << 4);
        af[kh][m] = *(const bf16x8*)(As + byte);
      }
#pragma unroll
      for (int n = 0; n < 4; ++n) {
        int r = wc * 64 + n * 16 + l15;
        int byte = (r * 128 + kh * 64 + l4 * 16) ^ ((r & 7) << 4);
        bfr[kh][n] = *(const bf16x8*)(Bs[s] + byte);
      }
    }
#pragma unroll
    for (int kh = 0; kh < 2; ++kh)
#pragma unroll
      for (int m = 0; m < 4; ++m)
#pragma unroll
        for (int n = 0; n < 4; ++n)
          acc[m][n] = __builtin_amdgcn_mfma_f32_16x16x32_bf16(
              af[kh][m], bfr[kh][n], acc[m][n], 0, 0, 0);

    asm volatile("s_waitcnt lgkmcnt(0)" ::: "memory");  // own ds_reads retired
    __builtin_amdgcn_s_barrier();  // buffer-reuse fence (As, Bs[s^1])
  }

  if (which < 2) {
    unsigned short* Cp = dstQK + (size_t)which * 8388608;
#pragma unroll
    for (int n = 0; n < 4; ++n) {
      int col = n0 + wc * 64 + n * 16 + l15;
      float bc = bias[col];
#pragma unroll
      for (int m = 0; m < 4; ++m) {
        int rowb = m0 + wr * 64 + m * 16 + l4 * 4;
#pragma unroll
        for (int r = 0; r < 4; ++r) {
          float val = (acc[m][n][r] + bc) * osc;
          Cp[(size_t)(rowb + r) * N + col] = f2bf(val);
        }
      }
    }
  } else {
    // V: write transposed Vt[((b*16+h)*64+d)*2048 + s], 8B per (m,n)
#pragma unroll
    for (int n = 0; n < 4; ++n) {
      int dcol = n0 + wc * 64 + n * 16 + l15;  // h*64+d in 0..1023
      float bc = bias[dcol];
#pragma unroll
      for (int m = 0; m < 4; ++m) {
        int srow = m0 + wr * 64 + m * 16 + l4 * 4;  // b*2048+s, 4-aligned
        int bb = srow >> 11, s = srow & 2047;
        ushort4v o;
#pragma unroll
        for (int r = 0; r < 4; ++r) o[r] = f2bf(acc[m][n][r] + bc);
        *(ushort4v*)(Vt + ((size_t)(bb * 1024 + dcol)) * 2048 + s) = o;
      }
    }
  }
}

// ---------------- out GEMM: counted-vmcnt dbuf pipeline (R18 GREEN) --------
__launch_bounds__(256)
__global__ void gemm_out(const unsigned short* __restrict__ Ab,
                         const unsigned short* __restrict__ Bw,
                         const float* __restrict__ bias,
                         float* __restrict__ Cp, int M, int N, int K) {
  __shared__ __align__(16) unsigned char As[2][16384];
  __shared__ __align__(16) unsigned char Bs[2][16384];
  const int cpx = gridDim.x >> 3;
  const int bid = (blockIdx.x & 7) * cpx + (blockIdx.x >> 3);
  const int nb = N >> 7;
  const int bm = bid / nb, bn = bid % nb;
  const int m0 = bm << 7, n0 = bn << 7;
  const int t = threadIdx.x, lane = t & 63, wv = t >> 6;
  const int wr = wv >> 1, wc = wv & 1;
  const int l15 = lane & 15, l4 = lane >> 4;

  f32x4 acc[4][4] = {};

  auto STAGE = [&](int k0, int s) {
#pragma unroll
    for (int j = 0; j < 4; ++j) {
      int p = (wv * 4 + j) * 1024 + lane * 16;
      int row = p >> 7;
      int cb = (p & 127) ^ ((row & 7) << 4);
      gload_lds16(Bw + (size_t)(n0 + row) * K + k0 + (cb >> 1),
                  Bs[s] + (wv * 4 + j) * 1024);
      gload_lds16(Ab + (size_t)(m0 + row) * K + k0 + (cb >> 1),
                  As[s] + (wv * 4 + j) * 1024);
    }
  };

  STAGE(0, 0);
  const int nk = K >> 6;
  for (int i = 0; i < nk; ++i) {
    const int s = i & 1;
    if (i + 1 < nk) {
      STAGE((i + 1) << 6, s ^ 1);
      asm volatile("s_waitcnt vmcnt(8)" ::: "memory");
    } else {
      asm volatile("s_waitcnt vmcnt(0)" ::: "memory");
    }
    __builtin_amdgcn_s_barrier();  // tile i DMA visible to all waves

    bf16x8 af[2][4], bfr[2][4];
#pragma unroll
    for (int kh = 0; kh < 2; ++kh) {
#pragma unroll
      for (int m = 0; m < 4; ++m) {
        int r = wr * 64 + m * 16 + l15;
        int byte = (r * 128 + kh * 64 + l4 * 16) ^ ((r & 7) << 4);
        af[kh][m] = *(const bf16x8*)(As[s] + byte);
      }
#pragma unroll
      for (int n = 0; n < 4; ++n) {
        int r = wc * 64 + n * 16 + l15;
        int byte = (r * 128 + kh * 64 + l4 * 16) ^ ((r & 7) << 4);
        bfr[kh][n] = *(const bf16x8*)(Bs[s] + byte);
      }
    }
#pragma unroll
    for (int kh = 0; kh < 2; ++kh)
#pragma unroll
      for (int m = 0; m < 4; ++m)
#pragma unroll
        for (int n = 0; n < 4; ++n)
          acc[m][n] = __builtin_amdgcn_mfma_f32_16x16x32_bf16(
              af[kh][m], bfr[kh][n], acc[m][n], 0, 0, 0);

    asm volatile("s_waitcnt lgkmcnt(0)" ::: "memory");  // own ds_reads retired
    __builtin_amdgcn_s_barrier();  // buffer-reuse fence
  }

#pragma unroll
  for (int n = 0; n < 4; ++n) {
    int col = n0 + wc * 64 + n * 16 + l15;
    float bc = bias[col];
#pragma unroll
    for (int m = 0; m < 4; ++m) {
      int rowb = m0 + wr * 64 + m * 16 + l4 * 4;
#pragma unroll
      for (int r = 0; r < 4; ++r)
        Cp[(size_t)(rowb + r) * N + col] = acc[m][n][r] + bc;
    }
  }
}

// ---------------- flash attention (R12-R18 GREEN, byte-identical) ---------
// paired q-tiles, KVBLK=128 (2 subs per barrier), 2-phase dbuf + drain.
__launch_bounds__(256)
__global__ void attn_kernel(const unsigned short* __restrict__ Qh,
                            const unsigned short* __restrict__ Kh,
                            const unsigned short* __restrict__ Vt,
                            const int* __restrict__ pad,
                            const int* __restrict__ pcausal,
                            unsigned short* __restrict__ Out) {
  __shared__ __align__(16) unsigned char Ks[2][16384];
  __shared__ __align__(16) unsigned char Vs[2][16384];
  const int bid = (blockIdx.x & 7) * 64 + (blockIdx.x >> 3);  // XCD swizzle
  const int pr = bid & 7, h = (bid >> 3) & 15, b = bid >> 7;
  const int t = threadIdx.x, lane = t & 63, wv = t >> 6;
  const int l31 = lane & 31, hi = lane >> 5;
  const int causal = *pcausal;

  for (int half = 0; half < 2; ++half) {
    const int qt = half ? (15 - pr) : pr;
    const int q0 = qt << 7;
    const int qrow = q0 + wv * 32 + l31;  // this lane's q index
    const bool padded = (pad[b * SS + qrow] == 0);

    const unsigned short* Qb = Qh + ((size_t)(b * SS) + qrow) * HID + h * DH;
    bf16x8 qf[4];
#pragma unroll
    for (int dd = 0; dd < 4; ++dd) {
      qf[dd] = *(const bf16x8*)(Qb + dd * 16 + hi * 8);
      if (padded) qf[dd] = (bf16x8)0;
    }

    f32x16 oacc[2] = {};
    float m = -__builtin_inff(), l = 0.f;
    const int nkt = causal ? (qt + 1) : (SS >> 7);

    auto STAGE = [&](int kt, int s) {
#pragma unroll
      for (int j = 0; j < 4; ++j) {
        int p = (wv * 4 + j) * 1024 + lane * 16;
        int kr = p >> 7;
        int kcb = (p & 127) ^ ((kr & 7) << 4);
        gload_lds16(Kh + ((size_t)(b * SS) + (kt << 7) + kr) * HID + h * DH +
                        (kcb >> 1),
                    Ks[s] + (wv * 4 + j) * 1024);
        int vr = p >> 8;
        int vcb = (p & 255) ^ ((vr & 15) << 4);
        gload_lds16(Vt + ((size_t)((b * NH + h) * DH + vr)) * SS + (kt << 7) +
                        (vcb >> 1),
                    Vs[s] + (wv * 4 + j) * 1024);
      }
    };

    if (half) __syncthreads();  // protect buffers from previous half's reads
    STAGE(0, 0);
    for (int kt = 0; kt < nkt; ++kt) {
      asm volatile("s_waitcnt vmcnt(0)" ::: "memory");  // own DMA drained
      __syncthreads();            // all waves' tile-kt DMA now visible
      if (kt + 1 < nkt) STAGE(kt + 1, (kt + 1) & 1);  // prefetch next
      const unsigned char* Kb = Ks[kt & 1];
      const unsigned char* Vb = Vs[kt & 1];

#pragma unroll
      for (int sub = 0; sub < 2; ++sub) {
        const int k0 = (kt << 7) + (sub << 6);
        const bool active = (!causal) || (k0 <= q0 + wv * 32 + 31);
        if (!active) continue;
        // S^T = K * Q : out row = k, col = q
        f32x16 sacc[2] = {};
#pragma unroll
        for (int kb = 0; kb < 2; ++kb) {
#pragma unroll
          for (int dd = 0; dd < 4; ++dd) {
            int krow = sub * 64 + kb * 32 + l31;
            int byte = (krow * 128 + dd * 32 + hi * 16) ^ ((krow & 7) << 4);
            bf16x8 kf = *(const bf16x8*)(Kb + byte);
            sacc[kb] = __builtin_amdgcn_mfma_f32_32x32x16_bf16(kf, qf[dd],
                                                               sacc[kb], 0, 0, 0);
          }
        }
        // causal mask (diagonal sub-tiles only)
        if (causal && (k0 + 63 > q0 + wv * 32)) {
#pragma unroll
          for (int kb = 0; kb < 2; ++kb)
#pragma unroll
            for (int r = 0; r < 16; ++r) {
              int kidx = k0 + kb * 32 + (r & 3) + 8 * (r >> 2) + 4 * hi;
              if (kidx > qrow) sacc[kb][r] = -__builtin_inff();
            }
        }
        // row max (max3-fused tree) + partner exchange
        float ta = fmaxf(sacc[0][0], sacc[0][1]);
        float tb = fmaxf(sacc[0][2], sacc[0][3]);
#pragma unroll
        for (int r = 4; r < 16; r += 4) {
          ta = fmaxf(ta, fmaxf(sacc[0][r], sacc[0][r + 1]));
          tb = fmaxf(tb, fmaxf(sacc[0][r + 2], sacc[0][r + 3]));
        }
#pragma unroll
        for (int r = 0; r < 16; r += 4) {
          ta = fmaxf(ta, fmaxf(sacc[1][r], sacc[1][r + 1]));
          tb = fmaxf(tb, fmaxf(sacc[1][r + 2], sacc[1][r + 3]));
        }
        float tmax = fmaxf(ta, tb);
        tmax = fmaxf(tmax, __shfl_xor(tmax, 32));
        // defer-max: rescale only when wave-any growth > 8
        if (__any(tmax > m + 8.0f)) {
          float mnew = fmaxf(m, tmax);
          float corr = __builtin_amdgcn_exp2f(m - mnew);
          m = mnew;
          l *= corr;
#pragma unroll
          for (int db = 0; db < 2; ++db)
#pragma unroll
            for (int r = 0; r < 16; ++r) oacc[db][r] *= corr;
        }
        float ls = 0.f;
#pragma unroll
        for (int kb = 0; kb < 2; ++kb)
#pragma unroll
          for (int r = 0; r < 16; ++r) {
            float p = __builtin_amdgcn_exp2f(sacc[kb][r] - m);
            sacc[kb][r] = p;
            ls += p;
          }
        l += ls;

        // pack P^T into PV B-fragments
        bf16x8 pf[4];
#pragma unroll
        for (int kb = 0; kb < 2; ++kb) {
          unsigned w0 = cvt_pk_bf16(sacc[kb][0], sacc[kb][1]);
          unsigned w1 = cvt_pk_bf16(sacc[kb][2], sacc[kb][3]);
          unsigned w2 = cvt_pk_bf16(sacc[kb][4], sacc[kb][5]);
          unsigned w3 = cvt_pk_bf16(sacc[kb][6], sacc[kb][7]);
          unsigned w4 = cvt_pk_bf16(sacc[kb][8], sacc[kb][9]);
          unsigned w5 = cvt_pk_bf16(sacc[kb][10], sacc[kb][11]);
          unsigned w6 = cvt_pk_bf16(sacc[kb][12], sacc[kb][13]);
          unsigned w7 = cvt_pk_bf16(sacc[kb][14], sacc[kb][15]);
          unsigned t0 = __shfl_xor(hi ? w0 : w2, 32);
          unsigned t1 = __shfl_xor(hi ? w1 : w3, 32);
          unsigned t2 = __shfl_xor(hi ? w4 : w6, 32);
          unsigned t3 = __shfl_xor(hi ? w5 : w7, 32);
          u32x4 lo, hf;
          lo[0] = hi ? t0 : w0;
          lo[1] = hi ? t1 : w1;
          lo[2] = hi ? w2 : t0;
          lo[3] = hi ? w3 : t1;
          hf[0] = hi ? t2 : w4;
          hf[1] = hi ? t3 : w5;
          hf[2] = hi ? w6 : t2;
          hf[3] = hi ? w7 : t3;
          pf[2 * kb] = __builtin_bit_cast(bf16x8, lo);
          pf[2 * kb + 1] = __builtin_bit_cast(bf16x8, hf);
        }
        // O^T += V^T * P^T   (V rows 256B, sub selects 128B half)
#pragma unroll
        for (int db = 0; db < 2; ++db) {
#pragma unroll
          for (int kk = 0; kk < 4; ++kk) {
            int drow = db * 32 + l31;
            int byte = (drow * 256 + sub * 128 + kk * 32 + hi * 16) ^
                       ((drow & 15) << 4);
            bf16x8 vf = *(const bf16x8*)(Vb + byte);
            oacc[db] = __builtin_amdgcn_mfma_f32_32x32x16_bf16(vf, pf[kk],
                                                               oacc[db], 0, 0, 0);
          }
        }
      }
    }

    float ltot = l + __shfl_xor(l, 32);
    float inv = 1.0f / ltot;
    size_t rowoff = ((size_t)(b * SS) + qrow) * HID + h * DH;
#pragma unroll
    for (int db = 0; db < 2; ++db) {
#pragma unroll
      for (int g = 0; g < 4; ++g) {
        ushort4v o;
#pragma unroll
        for (int j = 0; j < 4; ++j) o[j] = f2bf(oacc[db][4 * g + j] * inv);
        *(ushort4v*)(Out + rowoff + db * 32 + 8 * g + 4 * hi) = o;
      }
    }
  }
}

// ---------------- launch ----------------
extern "C" void kernel_launch(void* const* d_in, const int* in_sizes, int n_in,
                              void* d_out, int out_size, void* d_ws,
                              size_t ws_size, hipStream_t stream) {
  const float* q = (const float*)d_in[0];
  const float* k = (const float*)d_in[1];
  const float* v = (const float*)d_in[2];
  const int* pad = (const int*)d_in[3];
  const float* Wq = (const float*)d_in[4];
  const float* bq = (const float*)d_in[5];
  const float* Wk = (const float*)d_in[6];
  const float* bk = (const float*)d_in[7];
  const float* Wv = (const float*)d_in[8];
  const float* bv = (const float*)d_in[9];
  const float* Wo = (const float*)d_in[10];
  const float* bo = (const float*)d_in[11];
  const int* iscausal = (const int*)d_in[12];
  float* out = (float*)d_out;

  const float SCL = 0.18033688011112042f;  // (1/8) * log2(e)
  const int NQKV = BB * SS * HID;          // 8388608

  // ws (ushorts): Wcat 4x1M | Qh | Kh | Vt | Htmp   (75.5 MB)
  unsigned short* Wcat = (unsigned short*)d_ws;
  unsigned short* Wob = Wcat + 3145728;
  unsigned short* Qh = Wob + 1048576;
  unsigned short* Kh = Qh + (size_t)NQKV;
  unsigned short* Vtp = Kh + (size_t)NQKV;
  unsigned short* Htmp = Vtp + (size_t)NQKV;

  cvt4_weights<<<2048, 256, 0, stream>>>(Wq, Wk, Wv, Wo, Wcat);

  gemm_qkv<<<1536, 256, 0, stream>>>(q, k, v, Wcat, bq, bk, bv, Qh, Vtp, SCL);

  attn_kernel<<<512, 256, 0, stream>>>(Qh, Kh, Vtp, pad, iscausal, Htmp);

  gemm_out<<<512, 256, 0, stream>>>(Htmp, Wob, bo, out, 8192, 1024, 1024);
}